// Round 8
// baseline (1011.218 us; speedup 1.0000x reference)
//
#include <hip/hip_runtime.h>
#include <cstdint>
#include <cmath>

#define TD 256
#define TE 256
#define NB 8
#define DD 512
#define DIN 80
#define NMEL 80

typedef unsigned long long u64;

// ---------------------------------------------------------------------------
// Generic tiled f32 GEMM + bias: C[M,N] = A[M,K] @ B[K,N] + bias[N]
// Requires M%64==0, N%64==0, K%16==0. 256 threads, 64x64 tile, 4x4 per thread.
// ---------------------------------------------------------------------------
__global__ __launch_bounds__(256) void gemm_bias_k(const float* __restrict__ A,
    const float* __restrict__ B, const float* __restrict__ bias,
    float* __restrict__ C, int M, int N, int K)
{
    __shared__ float As[64][17];
    __shared__ __align__(16) float Bs[16][64];
    const int tid = threadIdx.x;
    const int tx = tid & 15, ty = tid >> 4;
    const int n0 = blockIdx.x * 64, m0 = blockIdx.y * 64;
    float acc[4][4] = {};
    for (int k0 = 0; k0 < K; k0 += 16) {
#pragma unroll
        for (int i = 0; i < 4; ++i) {
            int lin = tid + i * 256;
            int k = lin & 15, m = lin >> 4;
            As[m][k] = A[(size_t)(m0 + m) * K + k0 + k];
        }
#pragma unroll
        for (int i = 0; i < 4; ++i) {
            int lin = tid + i * 256;
            int n = lin & 63, k = lin >> 6;
            Bs[k][n] = B[(size_t)(k0 + k) * N + n0 + n];
        }
        __syncthreads();
#pragma unroll
        for (int kk = 0; kk < 16; ++kk) {
            float a0 = As[ty * 4 + 0][kk], a1 = As[ty * 4 + 1][kk];
            float a2 = As[ty * 4 + 2][kk], a3 = As[ty * 4 + 3][kk];
            const float4 b4 = *(const float4*)&Bs[kk][tx * 4];
            acc[0][0] += a0 * b4.x; acc[0][1] += a0 * b4.y; acc[0][2] += a0 * b4.z; acc[0][3] += a0 * b4.w;
            acc[1][0] += a1 * b4.x; acc[1][1] += a1 * b4.y; acc[1][2] += a1 * b4.z; acc[1][3] += a1 * b4.w;
            acc[2][0] += a2 * b4.x; acc[2][1] += a2 * b4.y; acc[2][2] += a2 * b4.z; acc[2][3] += a2 * b4.w;
            acc[3][0] += a3 * b4.x; acc[3][1] += a3 * b4.y; acc[3][2] += a3 * b4.z; acc[3][3] += a3 * b4.w;
        }
        __syncthreads();
    }
    const float4 bv = *(const float4*)&bias[n0 + tx * 4];
#pragma unroll
    for (int i = 0; i < 4; ++i) {
        float4 o;
        o.x = acc[i][0] + bv.x; o.y = acc[i][1] + bv.y;
        o.z = acc[i][2] + bv.z; o.w = acc[i][3] + bv.w;
        *(float4*)&C[(size_t)(m0 + ty * 4 + i) * N + n0 + tx * 4] = o;
    }
}

// ---------------------------------------------------------------------------
// Persistent LSTM. Grid = 256 WGs (cooperative): batch b = blockIdx&7,
// group g = blockIdx>>3 (WG owns h-cols [16g,16g+16)).
// Lane mapping (per wave wv): kq = lane>>4 (K-quarter), idx = lane&15,
//   gate = idx>>2 (i,f,g,o), hoff = idx&3; wave owns h-cols 16g+4wv..+3.
// K-reduce = 2x shfl_xor (no LDS); activations branch-free on ALL lanes via
// exp2 (tanh(z)=2*sigmoid(2z)-1 folded into per-lane consts); lanes 0-3 of
// each wave hold c and publish independently. ONE __syncthreads per step;
// h_s double-buffered (stride 136 pad -> kq-group bases in distinct banks).
// h exchange: hpub[2][NB][512] of u64 {tag(hi32), h(lo32)} — one relaxed
// agent-scope 8B atomic store; consumer's poll load IS the data load.
// ---------------------------------------------------------------------------
__global__ __launch_bounds__(256, 1) void lstm_k(const float* __restrict__ Zx,
    const float* __restrict__ Wr, float* __restrict__ hs,
    u64* __restrict__ hpub,
    float* __restrict__ outh, float* __restrict__ outc)
{
    __shared__ __align__(16) float h_s[2][544];   // 4 groups x 136 (128+8 pad)
    const int b = blockIdx.x & 7;
    const int g = blockIdx.x >> 3;
    const int tid = threadIdx.x;
    const int wv = tid >> 6;
    const int lane = tid & 63;
    const int kq = lane >> 4;
    const int idx = lane & 15;
    const int gate = idx >> 2;          // 0=i 1=f 2=g(cell) 3=o
    const int hoff = idx & 3;
    const int hcol = (g << 4) | (wv << 2) | hoff;   // 0..511
    const int gcol = (gate << 9) | hcol;            // 0..2047
    const float L2E = 1.442695040888963f;
    const bool isG = (gate == 2);
    const float mscale = isG ? (-2.f * L2E) : (-L2E);  // exp2(z*mscale) = exp(-z) or exp(-2z)
    const float aA = isG ? 2.f : 1.f;   // act = aA * rcp(1+e) + aB
    const float aB = isG ? -1.f : 0.f;

    // Wr slice: w[i] = Wr[kq*128+i][gcol]
    float w[128];
    {
        const float* wb = Wr + (size_t)(kq * 128) * 2048 + gcol;
#pragma unroll
        for (int i = 0; i < 128; ++i) w[i] = wb[(size_t)i * 2048];
    }
    float creg = 0.f, hlast = 0.f;      // live in lanes 0-3 of each wave
    u64* const pub0 = hpub + (size_t)b * 512;
    u64* const pub1 = hpub + (size_t)(8 + b) * 512;

    for (int t = 0; t < TD; ++t) {
        // prefetch this step's Zx (waitcnt lands after the reduce)
        float zx = Zx[(size_t)(b * TD + t) * 2048 + gcol];

        // spin directly on the published {tag,h} packets for step t
        {
            u64* const pr = (t & 1) ? pub1 : pub0;
            const unsigned stag = (unsigned)t;
            u64 v0 = 0, v1 = 0;
            bool d0 = false, d1 = false;
            for (;;) {
                if (!d0) { v0 = __hip_atomic_load(pr + tid, __ATOMIC_RELAXED, __HIP_MEMORY_SCOPE_AGENT);
                           d0 = ((unsigned)(v0 >> 32) == stag); }
                if (!d1) { v1 = __hip_atomic_load(pr + tid + 256, __ATOMIC_RELAXED, __HIP_MEMORY_SCOPE_AGENT);
                           d1 = ((unsigned)(v1 >> 32) == stag); }
                if (d0 && d1) break;
                __builtin_amdgcn_s_sleep(1);
            }
            float* hb = h_s[t & 1];
            const int j0 = tid, j1 = tid + 256;
            hb[(j0 >> 7) * 136 + (j0 & 127)] = __uint_as_float((unsigned)v0);
            hb[(j1 >> 7) * 136 + (j1 & 127)] = __uint_as_float((unsigned)v1);
        }
        __syncthreads();   // the only barrier per step

        // partial dot over this lane's K-quarter
        float acc = 0.f;
        {
            const float4* h4 = (const float4*)(h_s[t & 1] + kq * 136);
#pragma unroll
            for (int i = 0; i < 32; ++i) {
                float4 h = h4[i];
                acc += w[4 * i + 0] * h.x;
                acc += w[4 * i + 1] * h.y;
                acc += w[4 * i + 2] * h.z;
                acc += w[4 * i + 3] * h.w;
            }
        }
        // K-reduce across the 4 kq groups (lanes l, l^16, l^32, l^48)
        acc += __shfl_xor(acc, 16);
        acc += __shfl_xor(acc, 32);
        float z = acc + zx;
        // branch-free activation on ALL lanes (1 exp2 + 1 rcp)
        float e = __builtin_amdgcn_exp2f(z * mscale);
        float s = __builtin_amdgcn_rcpf(1.f + e);
        float act = fmaf(s, aA, aB);
        // gather i,f,g,o for this lane's hoff (valid in every kq group)
        const int basel = (lane & 48) | hoff;
        float ii = __shfl(act, basel);
        float ff = __shfl(act, basel | 4);
        float gg = __shfl(act, basel | 8);
        float oo = __shfl(act, basel | 12);
        if (lane < 4) {                 // state-owning lanes (hoff=lane, kq=0)
            creg = fmaf(ff, creg, ii * gg);
            float e2 = __builtin_amdgcn_exp2f(creg * (-2.f * L2E));
            float th = fmaf(2.f, __builtin_amdgcn_rcpf(1.f + e2), -1.f);  // tanh(c)
            hlast = oo * th;
            // publish {tag=t+1, h} FIRST (critical path), then hs (HBM)
            u64 pv = ((u64)(unsigned)(t + 1) << 32) | (u64)__float_as_uint(hlast);
            u64* const pw = (t & 1) ? pub0 : pub1;
            __hip_atomic_store(pw + hcol, pv, __ATOMIC_RELAXED, __HIP_MEMORY_SCOPE_AGENT);
            hs[(size_t)(b * TD + t) * 512 + hcol] = hlast;
        }
    }
    if (lane < 4) {
        outh[b * 512 + hcol] = hlast;
        outc[b * 512 + hcol] = creg;
    }
}

// ---------------------------------------------------------------------------
// Fused attention: scores (tanh(half1[e]+half2[d]) @ W3 + b3) -> softmax(e)
// -> weighted = attn @ attended. One WG = (batch, 4 d-rows). 512 WGs.
// ---------------------------------------------------------------------------
__global__ __launch_bounds__(256) void attn_k(const float* __restrict__ half1,
    const float* __restrict__ half2, const float* __restrict__ att,
    const float* __restrict__ W3, const float* __restrict__ b3,
    float* __restrict__ wgt)
{
    __shared__ __align__(16) float h2s[4][512];
    __shared__ __align__(16) float sc[4][256];
    __shared__ __align__(16) float av[8][512];
    const int tid = threadIdx.x;
    const int bb = blockIdx.x >> 6;
    const int d0 = (blockIdx.x & 63) * 4;
    const float C2 = 2.885390081777927f;  // 2*log2(e)

    // stage half2 rows, pre-scaled by C2
#pragma unroll
    for (int i = 0; i < 8; ++i) {
        int lin = tid + i * 256;
        int r = lin >> 9, k = lin & 511;
        h2s[r][k] = half2[(size_t)(bb * TD + d0 + r) * 512 + k] * C2;
    }
    __syncthreads();
    // phase 2: thread e = tid computes scores for the 4 rows
    {
        const float* h1p = half1 + (size_t)(bb * TE + tid) * 512;
        float accs[4] = {0.f, 0.f, 0.f, 0.f};
        for (int k = 0; k < 512; k += 4) {
            float4 h1 = *(const float4*)(h1p + k);
            float4 w3 = *(const float4*)(W3 + k);
            float u0 = h1.x * C2, u1 = h1.y * C2, u2 = h1.z * C2, u3 = h1.w * C2;
#pragma unroll
            for (int r = 0; r < 4; ++r) {
                float t0 = 1.f - 2.f * __builtin_amdgcn_rcpf(__builtin_amdgcn_exp2f(u0 + h2s[r][k + 0]) + 1.f);
                float t1 = 1.f - 2.f * __builtin_amdgcn_rcpf(__builtin_amdgcn_exp2f(u1 + h2s[r][k + 1]) + 1.f);
                float t2 = 1.f - 2.f * __builtin_amdgcn_rcpf(__builtin_amdgcn_exp2f(u2 + h2s[r][k + 2]) + 1.f);
                float t3 = 1.f - 2.f * __builtin_amdgcn_rcpf(__builtin_amdgcn_exp2f(u3 + h2s[r][k + 3]) + 1.f);
                accs[r] += t0 * w3.x + t1 * w3.y + t2 * w3.z + t3 * w3.w;
            }
        }
        const float b3v = b3[0];
#pragma unroll
        for (int r = 0; r < 4; ++r) sc[r][tid] = accs[r] + b3v;
    }
    __syncthreads();
    // phase 3: softmax — wave w handles row w
    {
        const int r = tid >> 6, l = tid & 63;
        float4 v = *(const float4*)&sc[r][l * 4];
        float mx = fmaxf(fmaxf(v.x, v.y), fmaxf(v.z, v.w));
#pragma unroll
        for (int off = 32; off; off >>= 1) mx = fmaxf(mx, __shfl_xor(mx, off));
        const float L2E = 1.44269504089f;
        float e0 = __builtin_amdgcn_exp2f((v.x - mx) * L2E);
        float e1 = __builtin_amdgcn_exp2f((v.y - mx) * L2E);
        float e2 = __builtin_amdgcn_exp2f((v.z - mx) * L2E);
        float e3 = __builtin_amdgcn_exp2f((v.w - mx) * L2E);
        float s = e0 + e1 + e2 + e3;
#pragma unroll
        for (int off = 32; off; off >>= 1) s += __shfl_xor(s, off);
        float inv = 1.f / s;
        float4 p; p.x = e0 * inv; p.y = e1 * inv; p.z = e2 * inv; p.w = e3 * inv;
        *(float4*)&sc[r][l * 4] = p;
    }
    __syncthreads();
    // phase 4: weighted = attn @ attended
    float acc[4][2] = {};
    for (int e0 = 0; e0 < TE; e0 += 8) {
#pragma unroll
        for (int i = 0; i < 16; ++i) {
            int lin = tid + i * 256;
            int e = lin >> 9, k = lin & 511;
            av[e][k] = att[(size_t)(bb * TE + e0 + e) * 512 + k];
        }
        __syncthreads();
#pragma unroll
        for (int ee = 0; ee < 8; ++ee) {
            float x0 = av[ee][tid], x1 = av[ee][tid + 256];
#pragma unroll
            for (int r = 0; r < 4; ++r) {
                float p = sc[r][e0 + ee];
                acc[r][0] += p * x0;
                acc[r][1] += p * x1;
            }
        }
        __syncthreads();
    }
#pragma unroll
    for (int r = 0; r < 4; ++r) {
        wgt[(size_t)(bb * TD + d0 + r) * 512 + tid] = acc[r][0];
        wgt[(size_t)(bb * TD + d0 + r) * 512 + tid + 256] = acc[r][1];
    }
}

// ---------------------------------------------------------------------------
// out = concat(x, weighted) @ Wout + bout.  M=2048, N=80, K=1024.
// K split over blockIdx.y (4 chunks of 256); partials atomicAdd'd into out
// (pre-zeroed). ks==0 adds bias.
// ---------------------------------------------------------------------------
__global__ __launch_bounds__(256) void outgemm_k(const float* __restrict__ x,
    const float* __restrict__ wgt, const float* __restrict__ Wout,
    const float* __restrict__ bout, float* __restrict__ out)
{
    __shared__ float As[64][17];
    __shared__ float Bs[16][80];
    const int tid = threadIdx.x;
    const int tx = tid & 15, ty = tid >> 4;
    const int m0 = blockIdx.x * 64;
    const int ks = blockIdx.y;
    float acc[4][5] = {};
    for (int kt = 0; kt < 16; ++kt) {
        const int k0 = ks * 256 + kt * 16;
        const float* src = (k0 < 512) ? x : wgt;
        const int kk0 = (k0 < 512) ? k0 : (k0 - 512);
#pragma unroll
        for (int i = 0; i < 4; ++i) {
            int lin = tid + i * 256;
            int k = lin & 15, m = lin >> 4;
            As[m][k] = src[(size_t)(m0 + m) * 512 + kk0 + k];
        }
#pragma unroll
        for (int i = 0; i < 5; ++i) {
            int lin = tid + i * 256;
            int n = lin % 80, k = lin / 80;
            Bs[k][n] = Wout[(size_t)(k0 + k) * 80 + n];
        }
        __syncthreads();
#pragma unroll
        for (int kk = 0; kk < 16; ++kk) {
            float a[4], bv[5];
#pragma unroll
            for (int i = 0; i < 4; ++i) a[i] = As[ty * 4 + i][kk];
#pragma unroll
            for (int j = 0; j < 5; ++j) bv[j] = Bs[kk][tx * 5 + j];
#pragma unroll
            for (int i = 0; i < 4; ++i)
#pragma unroll
                for (int j = 0; j < 5; ++j) acc[i][j] += a[i] * bv[j];
        }
        __syncthreads();
    }
#pragma unroll
    for (int i = 0; i < 4; ++i) {
#pragma unroll
        for (int j = 0; j < 5; ++j) {
            float v = acc[i][j];
            if (ks == 0) v += bout[tx * 5 + j];
            atomicAdd(&out[(size_t)(m0 + ty * 4 + i) * 80 + tx * 5 + j], v);
        }
    }
}

// ---------------------------------------------------------------------------
extern "C" void kernel_launch(void* const* d_in, const int* in_sizes, int n_in,
                              void* d_out, int out_size, void* d_ws, size_t ws_size,
                              hipStream_t stream)
{
    (void)in_sizes; (void)n_in; (void)out_size; (void)ws_size;
    const float* inputs = (const float*)d_in[0];   // [8,256,80]
    const float* att    = (const float*)d_in[1];   // [8,256,512]
    const float* Wk     = (const float*)d_in[2];   // [80,2048]
    const float* Wr     = (const float*)d_in[3];   // [512,2048]
    const float* lb     = (const float*)d_in[4];   // [2048]
    const float* W1     = (const float*)d_in[5];   // [512,512]
    const float* b1     = (const float*)d_in[6];   // [512]
    const float* W3     = (const float*)d_in[7];   // [512]
    const float* b3     = (const float*)d_in[8];   // [1]
    const float* Wout   = (const float*)d_in[9];   // [1024,80]
    const float* bout   = (const float*)d_in[10];  // [80]

    float* out  = (float*)d_out;          // [2048,80]
    float* outh = out + 2048 * 80;        // [8,512]
    float* outc = outh + 8 * 512;         // [8,512]

    char* ws = (char*)d_ws;
    float* Zx    = (float*)(ws);                      // 16 MB  [2048,2048]
    float* half1 = (float*)(ws + (16u << 20));        // 4 MB   [2048,512]
    float* half2 = (float*)(ws + (20u << 20));        // 4 MB   [2048,512]
    float* hsx   = (float*)(ws + (24u << 20));        // 4 MB   [2048,512]  (x = LSTM hidden states)
    float* wgt   = (float*)(ws + (28u << 20));        // 4 MB   [2048,512]
    u64*   hpub  = (u64*)(ws + (32u << 20));          // 64 KB  hpub[2][8][512] {tag,h}

    // zero hpub (kills stale tags from prior graph replay); zero out (atomicAdd target)
    (void)hipMemsetAsync(ws + (32u << 20), 0, 2 * 8 * 512 * sizeof(u64), stream);
    (void)hipMemsetAsync(d_out, 0, (size_t)2048 * 80 * 4, stream);

    // Zx = inputs @ Wk + lstm_b      [2048,80]x[80,2048]
    gemm_bias_k<<<dim3(32, 32), 256, 0, stream>>>(inputs, Wk, lb, Zx, 2048, 2048, 80);
    // half1 = attended @ W1 + b1     [2048,512]x[512,512]
    gemm_bias_k<<<dim3(8, 32), 256, 0, stream>>>(att, W1, b1, half1, 2048, 512, 512);

    // LSTM (cooperative, 256 WGs x 256 threads)
    void* args[] = { (void*)&Zx, (void*)&Wr, (void*)&hsx, (void*)&hpub,
                     (void*)&outh, (void*)&outc };
    (void)hipLaunchCooperativeKernel((void*)lstm_k, dim3(256), dim3(256), args, 0, stream);

    // half2 = x @ W1 + b1
    gemm_bias_k<<<dim3(8, 32), 256, 0, stream>>>(hsx, W1, b1, half2, 2048, 512, 512);
    // fused scores/softmax/weighted
    attn_k<<<dim3(512), 256, 0, stream>>>(half1, half2, att, W3, b3, wgt);
    // out = [x | weighted] @ Wout + bout
    outgemm_k<<<dim3(32, 4), 256, 0, stream>>>(hsx, wgt, Wout, bout, out);
}

// Round 10
// 912.126 us; speedup vs baseline: 1.1086x; 1.1086x over previous
//
#include <hip/hip_runtime.h>
#include <cstdint>
#include <cmath>

#define TD 256
#define TE 256
#define NB 8
#define DD 512
#define DIN 80
#define NMEL 80

typedef unsigned long long u64;

// ---------------------------------------------------------------------------
// Shared tiled f32 GEMM + bias body: C[M,N] = A[M,K] @ B[K,N] + bias[N]
// 256 threads, 64x64 tile, 4x4 per thread. M%64==0, N%64==0, K%16==0.
// ---------------------------------------------------------------------------
__device__ __forceinline__ void gemm_body(const float* __restrict__ A,
    const float* __restrict__ B, const float* __restrict__ bias,
    float* __restrict__ C, int N, int K, int m0, int n0)
{
    __shared__ float As[64][17];
    __shared__ __align__(16) float Bs[16][64];
    const int tid = threadIdx.x;
    const int tx = tid & 15, ty = tid >> 4;
    float acc[4][4] = {};
    for (int k0 = 0; k0 < K; k0 += 16) {
#pragma unroll
        for (int i = 0; i < 4; ++i) {
            int lin = tid + i * 256;
            int k = lin & 15, m = lin >> 4;
            As[m][k] = A[(size_t)(m0 + m) * K + k0 + k];
        }
#pragma unroll
        for (int i = 0; i < 4; ++i) {
            int lin = tid + i * 256;
            int n = lin & 63, k = lin >> 6;
            Bs[k][n] = B[(size_t)(k0 + k) * N + n0 + n];
        }
        __syncthreads();
#pragma unroll
        for (int kk = 0; kk < 16; ++kk) {
            float a0 = As[ty * 4 + 0][kk], a1 = As[ty * 4 + 1][kk];
            float a2 = As[ty * 4 + 2][kk], a3 = As[ty * 4 + 3][kk];
            const float4 b4 = *(const float4*)&Bs[kk][tx * 4];
            acc[0][0] += a0 * b4.x; acc[0][1] += a0 * b4.y; acc[0][2] += a0 * b4.z; acc[0][3] += a0 * b4.w;
            acc[1][0] += a1 * b4.x; acc[1][1] += a1 * b4.y; acc[1][2] += a1 * b4.z; acc[1][3] += a1 * b4.w;
            acc[2][0] += a2 * b4.x; acc[2][1] += a2 * b4.y; acc[2][2] += a2 * b4.z; acc[2][3] += a2 * b4.w;
            acc[3][0] += a3 * b4.x; acc[3][1] += a3 * b4.y; acc[3][2] += a3 * b4.z; acc[3][3] += a3 * b4.w;
        }
        __syncthreads();
    }
    const float4 bv = *(const float4*)&bias[n0 + tx * 4];
#pragma unroll
    for (int i = 0; i < 4; ++i) {
        float4 o;
        o.x = acc[i][0] + bv.x; o.y = acc[i][1] + bv.y;
        o.z = acc[i][2] + bv.z; o.w = acc[i][3] + bv.w;
        *(float4*)&C[(size_t)(m0 + ty * 4 + i) * N + n0 + tx * 4] = o;
    }
}

__global__ __launch_bounds__(256) void gemm_bias_k(const float* __restrict__ A,
    const float* __restrict__ B, const float* __restrict__ bias,
    float* __restrict__ C, int N, int K)
{
    gemm_body(A, B, bias, C, N, K, blockIdx.y * 64, blockIdx.x * 64);
}

// Fused independent pre-GEMMs: wg<1024 -> Zx = inputs@Wk+lb (2048x2048,K=80);
// else -> half1 = att@W1+b1 (2048x512,K=512). Branch is WG-uniform.
__global__ __launch_bounds__(256) void fused_pre_k(
    const float* __restrict__ inputs, const float* __restrict__ Wk,
    const float* __restrict__ lb, float* __restrict__ Zx,
    const float* __restrict__ att, const float* __restrict__ W1,
    const float* __restrict__ b1, float* __restrict__ half1)
{
    int wg = blockIdx.x;
    if (wg < 1024) {
        gemm_body(inputs, Wk, lb, Zx, 2048, 80, (wg >> 5) * 64, (wg & 31) * 64);
    } else {
        wg -= 1024;
        gemm_body(att, W1, b1, half1, 512, 512, (wg >> 3) * 64, (wg & 7) * 64);
    }
}

// ---------------------------------------------------------------------------
// Persistent LSTM — EXACT Round-3-measured version (586 us). Grid = 256 WGs
// (cooperative): batch b = blockIdx&7, group g = blockIdx>>3. Each WG owns 16
// h-cols -> 64 gate cols; Wr slice in VGPRs (128 f32/lane). h exchange:
// double-buffered hpub[2][NB][512] of u64 {tag(hi32), h(lo32)} — one relaxed
// agent-scope 8B atomic store; consumer's poll load IS the data load.
// ---------------------------------------------------------------------------
__global__ __launch_bounds__(256, 1) void lstm_k(const float* __restrict__ Zx,
    const float* __restrict__ Wr, float* __restrict__ hs,
    u64* __restrict__ hpub,
    float* __restrict__ outh, float* __restrict__ outc)
{
    __shared__ __align__(16) float h_s[512];
    __shared__ float part[256];
    const int b = blockIdx.x & 7;
    const int g = blockIdx.x >> 3;
    const int tid = threadIdx.x;
    const int wv = tid >> 6;
    const int lane = tid & 63;
    const int gcol = ((lane >> 4) << 9) | (g << 4) | (lane & 15);
    const int col = (g << 4) | (lane & 15);

    float w[128];
    {
        const float* wb = Wr + (size_t)(wv * 128) * 2048 + gcol;
#pragma unroll
        for (int i = 0; i < 128; ++i) w[i] = wb[(size_t)i * 2048];
    }
    float creg = 0.f, hlast = 0.f;
    u64* const pub0 = hpub + (size_t)b * 512;
    u64* const pub1 = hpub + (size_t)(8 + b) * 512;

    for (int t = 0; t < TD; ++t) {
        float zx = 0.f;
        if (wv == 0) zx = Zx[(size_t)(b * TD + t) * 2048 + gcol];

        {
            u64* const pr = (t & 1) ? pub1 : pub0;
            const unsigned stag = (unsigned)t;
            u64 v0 = 0, v1 = 0;
            bool d0 = false, d1 = false;
            for (;;) {
                if (!d0) { v0 = __hip_atomic_load(pr + tid, __ATOMIC_RELAXED, __HIP_MEMORY_SCOPE_AGENT);
                           d0 = ((unsigned)(v0 >> 32) == stag); }
                if (!d1) { v1 = __hip_atomic_load(pr + tid + 256, __ATOMIC_RELAXED, __HIP_MEMORY_SCOPE_AGENT);
                           d1 = ((unsigned)(v1 >> 32) == stag); }
                if (d0 && d1) break;
                __builtin_amdgcn_s_sleep(1);
            }
            h_s[tid]       = __uint_as_float((unsigned)v0);
            h_s[tid + 256] = __uint_as_float((unsigned)v1);
        }
        __syncthreads();

        float acc = 0.f;
        {
            const float4* h4 = (const float4*)(h_s + (wv << 7));
#pragma unroll
            for (int i = 0; i < 32; ++i) {
                float4 h = h4[i];
                acc += w[4 * i + 0] * h.x;
                acc += w[4 * i + 1] * h.y;
                acc += w[4 * i + 2] * h.z;
                acc += w[4 * i + 3] * h.w;
            }
        }
        part[tid] = acc;
        __syncthreads();
        if (wv == 0) {
            float z = part[lane] + part[64 + lane] + part[128 + lane] + part[192 + lane] + zx;
            float zf = __shfl(z, lane + 16);
            float zg = __shfl(z, lane + 32);
            float zo = __shfl(z, lane + 48);
            if (lane < 16) {
                float ig = 1.f / (1.f + expf(-z));
                float fg = 1.f / (1.f + expf(-zf));
                float gg = tanhf(zg);
                float og = 1.f / (1.f + expf(-zo));
                creg = fg * creg + ig * gg;
                hlast = og * tanhf(creg);
                u64 pv = ((u64)(unsigned)(t + 1) << 32) | (u64)__float_as_uint(hlast);
                u64* const pw = (t & 1) ? pub0 : pub1;
                __hip_atomic_store(pw + col, pv, __ATOMIC_RELAXED, __HIP_MEMORY_SCOPE_AGENT);
                hs[(size_t)(b * TD + t) * 512 + col] = hlast;
            }
        }
    }
    if (wv == 0 && lane < 16) {
        outh[b * 512 + col] = hlast;
        outc[b * 512 + col] = creg;
    }
}

// ---------------------------------------------------------------------------
// Fused attention v2: LDS-staged half1 (fixes the 64-way row-gather).
// scores = tanh(half1[e]+half2[d]) @ W3 + b3 -> softmax(e) -> attn @ att.
// One WG = (batch, 4 d-rows), 512 WGs. Per-element float op sequence is
// IDENTICAL to the previously-passing version (no reassociation).
// ---------------------------------------------------------------------------
__global__ __launch_bounds__(256) void attn_k(const float* __restrict__ half1,
    const float* __restrict__ half2, const float* __restrict__ att,
    const float* __restrict__ W3, const float* __restrict__ b3,
    float* __restrict__ wgt)
{
    __shared__ __align__(16) float h2s[4][512];
    __shared__ float h1s[256 * 33];          // 32-k chunk, pad 33: 2-way banks
    __shared__ __align__(16) float sc[4][256];
    __shared__ __align__(16) float av[8][512];
    const int tid = threadIdx.x;
    const int bb = blockIdx.x >> 6;
    const int d0 = (blockIdx.x & 63) * 4;
    const float C2 = 2.885390081777927f;     // 2*log2(e)

    // stage half2 rows, pre-scaled by C2
#pragma unroll
    for (int i = 0; i < 8; ++i) {
        int lin = tid + i * 256;
        int r = lin >> 9, k = lin & 511;
        h2s[r][k] = half2[(size_t)(bb * TD + d0 + r) * 512 + k] * C2;
    }

    // phase 2: k-chunked; thread e = tid accumulates scores for the 4 rows
    float accs[4] = {0.f, 0.f, 0.f, 0.f};
    for (int kc = 0; kc < 512; kc += 32) {
        // stage half1[256 e][32 k] coalesced (128B runs), pre-scaled by C2
#pragma unroll
        for (int i = 0; i < 32; ++i) {
            int lin = tid + i * 256;
            int e = lin >> 5, kk = lin & 31;
            h1s[e * 33 + kk] = half1[(size_t)(bb * TE + e) * 512 + kc + kk] * C2;
        }
        __syncthreads();   // first pass also covers h2s
        const float* myh1 = h1s + tid * 33;
#pragma unroll 8
        for (int kk = 0; kk < 32; ++kk) {
            float u = myh1[kk];
            float w = W3[kc + kk];
#pragma unroll
            for (int r = 0; r < 4; ++r) {
                float t = 1.f - 2.f * __builtin_amdgcn_rcpf(__builtin_amdgcn_exp2f(u + h2s[r][kc + kk]) + 1.f);
                accs[r] += t * w;
            }
        }
        __syncthreads();   // before restaging h1s
    }
    {
        const float b3v = b3[0];
#pragma unroll
        for (int r = 0; r < 4; ++r) sc[r][tid] = accs[r] + b3v;
    }
    __syncthreads();
    // phase 3: softmax — wave w handles row w
    {
        const int r = tid >> 6, l = tid & 63;
        float4 v = *(const float4*)&sc[r][l * 4];
        float mx = fmaxf(fmaxf(v.x, v.y), fmaxf(v.z, v.w));
#pragma unroll
        for (int off = 32; off; off >>= 1) mx = fmaxf(mx, __shfl_xor(mx, off));
        const float L2E = 1.44269504089f;
        float e0 = __builtin_amdgcn_exp2f((v.x - mx) * L2E);
        float e1 = __builtin_amdgcn_exp2f((v.y - mx) * L2E);
        float e2 = __builtin_amdgcn_exp2f((v.z - mx) * L2E);
        float e3 = __builtin_amdgcn_exp2f((v.w - mx) * L2E);
        float s = e0 + e1 + e2 + e3;
#pragma unroll
        for (int off = 32; off; off >>= 1) s += __shfl_xor(s, off);
        float inv = 1.f / s;
        float4 p; p.x = e0 * inv; p.y = e1 * inv; p.z = e2 * inv; p.w = e3 * inv;
        *(float4*)&sc[r][l * 4] = p;
    }
    __syncthreads();
    // phase 4: weighted = attn @ attended
    float acc[4][2] = {};
    for (int e0 = 0; e0 < TE; e0 += 8) {
#pragma unroll
        for (int i = 0; i < 16; ++i) {
            int lin = tid + i * 256;
            int e = lin >> 9, k = lin & 511;
            av[e][k] = att[(size_t)(bb * TE + e0 + e) * 512 + k];
        }
        __syncthreads();
#pragma unroll
        for (int ee = 0; ee < 8; ++ee) {
            float x0 = av[ee][tid], x1 = av[ee][tid + 256];
#pragma unroll
            for (int r = 0; r < 4; ++r) {
                float p = sc[r][e0 + ee];
                acc[r][0] += p * x0;
                acc[r][1] += p * x1;
            }
        }
        __syncthreads();
    }
#pragma unroll
    for (int r = 0; r < 4; ++r) {
        wgt[(size_t)(bb * TD + d0 + r) * 512 + tid] = acc[r][0];
        wgt[(size_t)(bb * TD + d0 + r) * 512 + tid + 256] = acc[r][1];
    }
}

// ---------------------------------------------------------------------------
// out = concat(x, weighted) @ Wout + bout.  M=2048, N=80, K=1024.
// K split over blockIdx.y (4 chunks of 256); atomicAdd into pre-zeroed out.
// ---------------------------------------------------------------------------
__global__ __launch_bounds__(256) void outgemm_k(const float* __restrict__ x,
    const float* __restrict__ wgt, const float* __restrict__ Wout,
    const float* __restrict__ bout, float* __restrict__ out)
{
    __shared__ float As[64][17];
    __shared__ float Bs[16][80];
    const int tid = threadIdx.x;
    const int tx = tid & 15, ty = tid >> 4;
    const int m0 = blockIdx.x * 64;
    const int ks = blockIdx.y;
    float acc[4][5] = {};
    for (int kt = 0; kt < 16; ++kt) {
        const int k0 = ks * 256 + kt * 16;
        const float* src = (k0 < 512) ? x : wgt;
        const int kk0 = (k0 < 512) ? k0 : (k0 - 512);
#pragma unroll
        for (int i = 0; i < 4; ++i) {
            int lin = tid + i * 256;
            int k = lin & 15, m = lin >> 4;
            As[m][k] = src[(size_t)(m0 + m) * 512 + kk0 + k];
        }
#pragma unroll
        for (int i = 0; i < 5; ++i) {
            int lin = tid + i * 256;
            int n = lin % 80, k = lin / 80;
            Bs[k][n] = Wout[(size_t)(k0 + k) * 80 + n];
        }
        __syncthreads();
#pragma unroll
        for (int kk = 0; kk < 16; ++kk) {
            float a[4], bv[5];
#pragma unroll
            for (int i = 0; i < 4; ++i) a[i] = As[ty * 4 + i][kk];
#pragma unroll
            for (int j = 0; j < 5; ++j) bv[j] = Bs[kk][tx * 5 + j];
#pragma unroll
            for (int i = 0; i < 4; ++i)
#pragma unroll
                for (int j = 0; j < 5; ++j) acc[i][j] += a[i] * bv[j];
        }
        __syncthreads();
    }
#pragma unroll
    for (int i = 0; i < 4; ++i) {
#pragma unroll
        for (int j = 0; j < 5; ++j) {
            float v = acc[i][j];
            if (ks == 0) v += bout[tx * 5 + j];
            atomicAdd(&out[(size_t)(m0 + ty * 4 + i) * 80 + tx * 5 + j], v);
        }
    }
}

// ---------------------------------------------------------------------------
extern "C" void kernel_launch(void* const* d_in, const int* in_sizes, int n_in,
                              void* d_out, int out_size, void* d_ws, size_t ws_size,
                              hipStream_t stream)
{
    (void)in_sizes; (void)n_in; (void)out_size; (void)ws_size;
    const float* inputs = (const float*)d_in[0];   // [8,256,80]
    const float* att    = (const float*)d_in[1];   // [8,256,512]
    const float* Wk     = (const float*)d_in[2];   // [80,2048]
    const float* Wr     = (const float*)d_in[3];   // [512,2048]
    const float* lb     = (const float*)d_in[4];   // [2048]
    const float* W1     = (const float*)d_in[5];   // [512,512]
    const float* b1     = (const float*)d_in[6];   // [512]
    const float* W3     = (const float*)d_in[7];   // [512]
    const float* b3     = (const float*)d_in[8];   // [1]
    const float* Wout   = (const float*)d_in[9];   // [1024,80]
    const float* bout   = (const float*)d_in[10];  // [80]

    float* out  = (float*)d_out;          // [2048,80]
    float* outh = out + 2048 * 80;        // [8,512]
    float* outc = outh + 8 * 512;         // [8,512]

    char* ws = (char*)d_ws;
    float* Zx    = (float*)(ws);                      // 16 MB  [2048,2048]
    float* half1 = (float*)(ws + (16u << 20));        // 4 MB   [2048,512]
    float* half2 = (float*)(ws + (20u << 20));        // 4 MB   [2048,512]
    float* hsx   = (float*)(ws + (24u << 20));        // 4 MB   [2048,512]
    float* wgt   = (float*)(ws + (28u << 20));        // 4 MB   [2048,512]
    u64*   hpub  = (u64*)(ws + (32u << 20));          // 64 KB  hpub[2][8][512]

    (void)hipMemsetAsync(ws + (32u << 20), 0, 2 * 8 * 512 * sizeof(u64), stream);
    (void)hipMemsetAsync(d_out, 0, (size_t)2048 * 80 * 4, stream);

    // fused: Zx = inputs@Wk+lb  AND  half1 = att@W1+b1
    fused_pre_k<<<dim3(1280), 256, 0, stream>>>(inputs, Wk, lb, Zx, att, W1, b1, half1);

    // LSTM (cooperative, 256 WGs x 256 threads)
    void* args[] = { (void*)&Zx, (void*)&Wr, (void*)&hsx, (void*)&hpub,
                     (void*)&outh, (void*)&outc };
    (void)hipLaunchCooperativeKernel((void*)lstm_k, dim3(256), dim3(256), args, 0, stream);

    // half2 = x @ W1 + b1
    gemm_bias_k<<<dim3(8, 32), 256, 0, stream>>>(hsx, W1, b1, half2, 512, 512);
    // fused scores/softmax/weighted (LDS-staged half1)
    attn_k<<<dim3(512), 256, 0, stream>>>(half1, half2, att, W3, b3, wgt);
    // out = [x | weighted] @ Wout + bout
    outgemm_k<<<dim3(32, 4), 256, 0, stream>>>(hsx, wgt, Wout, bout, out);
}